// Round 9
// baseline (164.077 us; speedup 1.0000x reference)
//
#include <hip/hip_runtime.h>
#include <hip/hip_bf16.h>

// Grouped masked GEMM (DeepSeekMOE up/gate + down), fp32 in/out, bf16 MFMA.
// G=8, M=32. up/gate: K=4096,N=2816. down: K=1408,N=4096. out: [G,32,5632] f32.
//
// R8 = R4 structure with the unit halved: n=16 units -> 3456 one-wave blocks,
// 13.5 independent waves/CU all co-resident (occupancy axis is the only one
// with measured signal: 3/CU=133-137us, 6.75/CU=122.9us). Everything else
// identical to R4: BK=128 (512B W row-visits), source-granule XOR swizzle,
// per-iter vmcnt(0), f32 X straight from L2, XCD-affine, mm==0 skip.

#define G_    8
#define M_    32
#define KUG   4096
#define NUG   2816
#define KDN   1408
#define NDN   4096
#define NOUT  (NUG + NDN)      // 5632
#define BN    16
#define BK    128
#define UPT   (NUG / BN)       // 176 up units per group
#define DNT   (NDN / BN)       // 256 down units per group
#define UPG   (UPT + DNT)      // 432 units per group; grid = 3456

typedef __attribute__((ext_vector_type(8))) short bf16x8;
typedef __attribute__((ext_vector_type(4))) float f32x4;

typedef __attribute__((address_space(3))) float        lds_f32;
typedef const __attribute__((address_space(1))) float  gbl_f32;

// fp32 -> bf16 RNE via compiler (m240: don't hand-write cvt_pk asm).
__device__ __forceinline__ short f2bf(float x) {
  union { __hip_bfloat16 h; short s; } u;
  u.h = __hip_bfloat16(x);
  return u.s;
}

__device__ __forceinline__ bf16x8 cvt8(f32x4 lo, f32x4 hi) {
  bf16x8 o;
#pragma unroll
  for (int j = 0; j < 4; ++j) { o[j] = f2bf(lo[j]); o[4 + j] = f2bf(hi[j]); }
  return o;
}

// Stage W tile [16 rows][BK=128 f32] via 8 gload_lds; instr i covers rows
// {2i,2i+1}, 512B contiguous per row (R4-proven sweet spot). LDS dest linear
// (gload_lds rule); bank-swizzle by source-granule XOR:
// LDS[row][q] = glob[row][q ^ (row&7)] (involution, re-applied on read).
__device__ __forceinline__ void stageW(const float* wg, float* wbuf, int K,
                                       int k0, int t) {
#pragma unroll
  for (int i = 0; i < 8; ++i) {
    int gid = i * 64 + t;
    int row = gid >> 5;           // 32 granules (16B) per row
    int q   = gid & 31;
    int qs  = q ^ (row & 7);
    __builtin_amdgcn_global_load_lds(
        (gbl_f32*)(wg + (size_t)row * K + k0 + qs * 4),
        (lds_f32*)(wbuf + gid * 4), 16, 0, 0);
  }
}

__global__ __launch_bounds__(64, 4) void moe_masked_gemm(
    const float* __restrict__ x_ug, const float* __restrict__ w_ug,
    const float* __restrict__ x_dn, const float* __restrict__ w_dn,
    const int* __restrict__ masked_m, float* __restrict__ out) {
  __shared__ float wbuf[BN * BK];   // 8 KB -> all 3456 blocks co-resident

  int b = blockIdx.x;
  int g = b & 7;                    // group -> XCD affinity (R4 mapping)
  int u = b >> 3;                   // unit 0..431: [0,176) up, [176,432) down

  const float* wg;
  const float* xf;
  int K, NIT, n0, colOff;
  bool is_up = (u < UPT);
  if (is_up) {
    K = KUG; NIT = KUG / BK; n0 = u * BN; colOff = 0;          // 32 iters
    wg = w_ug + ((size_t)g * NUG + n0) * KUG;
    xf = x_ug + (size_t)g * M_ * KUG;
  } else {
    int d = u - UPT;
    K = KDN; NIT = KDN / BK; n0 = d * BN; colOff = NUG;        // 11 iters
    wg = w_dn + ((size_t)g * NDN + n0) * KDN;
    xf = x_dn + (size_t)g * M_ * KDN;
  }

  int mm = masked_m[g];
  int t  = threadIdx.x;
  int r  = t & 15, q4 = t >> 4;     // frag coords
  int sk = r & 7;                   // read-side swizzle key (== row&7, row = r)

  f32x4 acc0 = {0.f, 0.f, 0.f, 0.f};   // m rows 0..15
  f32x4 acc1 = {0.f, 0.f, 0.f, 0.f};   // m rows 16..31

  if (mm != 0) {                    // mm==0: skip ALL reads, epilogue writes zeros
    for (int it = 0; it < NIT; ++it) {
      int k0 = it * BK;

      // Issue the W DMAs first, then X loads ride behind them.
      stageW(wg, wbuf, K, k0, t);

      // X fragments f32->bf16 (L2/L3-served; X[g] = 688 KB/XCD working set).
      bf16x8 xb[2][4];              // [m-frag][k-step]
#pragma unroll
      for (int mf = 0; mf < 2; ++mf)
#pragma unroll
        for (int ks = 0; ks < 4; ++ks) {
          const float* xp = xf + (size_t)(mf * 16 + r) * K + k0 + ks * 32 + q4 * 8;
          xb[mf][ks] = cvt8(*(const f32x4*)xp, *(const f32x4*)(xp + 4));
        }

      // gload_lds -> ds_read dep is invisible to the compiler (rule #18).
      asm volatile("s_waitcnt vmcnt(0)" ::: "memory");
      __builtin_amdgcn_sched_barrier(0);

      // 4 k-steps x 2 MFMA (m-frag 0/1), W row = r, swizzle-corrected reads.
      const float* rowp = wbuf + (size_t)r * BK;
#pragma unroll
      for (int ks = 0; ks < 4; ++ks) {
        int g0 = (ks * 4 + q4) * 2;
        f32x4 wlo = *(const f32x4*)(rowp + (((g0)     ^ sk) << 2));
        f32x4 whi = *(const f32x4*)(rowp + (((g0 + 1) ^ sk) << 2));
        bf16x8 bb = cvt8(wlo, whi);
        acc0 = __builtin_amdgcn_mfma_f32_16x16x32_bf16(xb[0][ks], bb, acc0, 0, 0, 0);
        acc1 = __builtin_amdgcn_mfma_f32_16x16x32_bf16(xb[1][ks], bb, acc1, 0, 0, 0);
      }
      // Next iter's gload_lds can't pass this iter's ds_reads (same LDS buffer,
      // in-order wave) — R4-validated single-buffer reuse.
    }
  }

  // Epilogue. C/D layout: col = lane&15, row = (lane>>4)*4 + i (m89-verified).
  // Lane stores col n0 + r for rows m = mf*16 + q4*4 + i; mask m >= mm.
  float* outg = out + (size_t)g * M_ * NOUT + colOff + n0;
#pragma unroll
  for (int i = 0; i < 4; ++i) {
    int m0 = q4 * 4 + i, m1 = 16 + m0;
    outg[(size_t)m0 * NOUT + r] = (m0 < mm) ? acc0[i] : 0.f;
    outg[(size_t)m1 * NOUT + r] = (m1 < mm) ? acc1[i] : 0.f;
  }
}

extern "C" void kernel_launch(void* const* d_in, const int* in_sizes, int n_in,
                              void* d_out, int out_size, void* d_ws, size_t ws_size,
                              hipStream_t stream) {
  const float* x_ug     = (const float*)d_in[0];
  const float* w_ug     = (const float*)d_in[1];
  const float* x_dn     = (const float*)d_in[2];
  const float* w_dn     = (const float*)d_in[3];
  const int*   masked_m = (const int*)d_in[4];
  float*       out      = (float*)d_out;

  moe_masked_gemm<<<dim3(G_ * UPG), dim3(64), 0, stream>>>(
      x_ug, w_ug, x_dn, w_dn, masked_m, out);
}

// Round 10
// 152.190 us; speedup vs baseline: 1.0781x; 1.0781x over previous
//
#include <hip/hip_runtime.h>
#include <hip/hip_bf16.h>

// Grouped masked GEMM (DeepSeekMOE up/gate + down), fp32 in/out, bf16 MFMA.
// G=8, M=32. up/gate: K=4096,N=2816. down: K=1408,N=4096. out: [G,32,5632] f32.
//
// R9 = R4 (n=32, 16KB LDS, 1728 one-wave blocks, all-resident, XCD-affine)
// with up-proj W visits lengthened 512B -> 1KB: each 256-k tile staged as two
// 16-row half-stages sharing the 16KB buffer; one DMA instr = one row's 1KB
// contiguous. Drains/byte and MFMA/byte identical to R4 (single-axis change).
// Counted vmcnt(16) pipelines the half-stages. X pre-converted to bf16 in d_ws
// (~270MB logical X, no f32 transients). Down-proj keeps R4's 512B path.

#define G_    8
#define M_    32
#define KUG   4096
#define NUG   2816
#define KDN   1408
#define NDN   4096
#define NOUT  (NUG + NDN)      // 5632
#define BN    32
#define UPT   (NUG / BN)       // 88 up units per group
#define DNT   (NDN / BN)       // 128 down units per group
#define UPG   (UPT + DNT)      // 216 units per group; grid = 1728
#define XUG_E (G_ * M_ * KUG)  // 1048576
#define XDN_E (G_ * M_ * KDN)  // 360448
#define XBF_BYTES ((size_t)(XUG_E + XDN_E) * 2)

typedef __attribute__((ext_vector_type(8))) short bf16x8;
typedef __attribute__((ext_vector_type(4))) float f32x4;

typedef __attribute__((address_space(3))) float        lds_f32;
typedef const __attribute__((address_space(1))) float  gbl_f32;

#define SCHED0() __builtin_amdgcn_sched_barrier(0)
#define VMC0()   asm volatile("s_waitcnt vmcnt(0)" ::: "memory")
#define VMC16()  asm volatile("s_waitcnt vmcnt(16)" ::: "memory")

// fp32 -> bf16 RNE via compiler (m240: don't hand-write cvt_pk asm).
__device__ __forceinline__ short f2bf(float x) {
  union { __hip_bfloat16 h; short s; } u;
  u.h = __hip_bfloat16(x);
  return u.s;
}
__device__ __forceinline__ bf16x8 cvt8(f32x4 lo, f32x4 hi) {
  bf16x8 o;
#pragma unroll
  for (int j = 0; j < 4; ++j) { o[j] = f2bf(lo[j]); o[4 + j] = f2bf(hi[j]); }
  return o;
}

// Prologue: f32 -> bf16 for both X arrays, one launch.
__global__ void cvt_x_kernel(const float* __restrict__ xu, const float* __restrict__ xd,
                             short* __restrict__ du, short* __restrict__ dd) {
  int i = blockIdx.x * 256 + threadIdx.x;
  const float* s; short* d;
  int j = i;
  if (i < XUG_E / 8) { s = xu; d = du; }
  else { s = xd; d = dd; j = i - XUG_E / 8; if (j >= XDN_E / 8) return; }
  f32x4 lo = *(const f32x4*)(s + (size_t)j * 8);
  f32x4 hi = *(const f32x4*)(s + (size_t)j * 8 + 4);
  *(bf16x8*)(d + (size_t)j * 8) = cvt8(lo, hi);
}

// ---- UP path: 16-row half-stage, BK=256, one instr = one row x 1KB ----
// LDS [16][256] f32; LDS row i holds global row (base16+i); source-granule
// XOR swizzle key (i&7) (involution; re-applied on read; preserves 128B lines).
__device__ __forceinline__ void stage16_1k(const float* wrows, float* wbuf,
                                           int k0, int t) {
#pragma unroll
  for (int i = 0; i < 16; ++i) {
    int qs = t ^ (i & 7);             // granule 0..63 within the row
    __builtin_amdgcn_global_load_lds(
        (gbl_f32*)(wrows + (size_t)i * KUG + k0 + qs * 4),
        (lds_f32*)(wbuf + i * 256 + t * 4), 16, 0, 0);
  }
}
// 8 swizzle-corrected ds_read_b128 pairs of LDS row r (2-way banked = free).
__device__ __forceinline__ void readW8(const float* wbuf, int r, int q4, int sk,
                                       f32x4 (&wr)[8][2]) {
  const float* rowp = wbuf + (size_t)r * 256;
#pragma unroll
  for (int ks = 0; ks < 8; ++ks) {
    int g0 = ks * 8 + q4 * 2;
    wr[ks][0] = *(const f32x4*)(rowp + (((g0)     ^ sk) << 2));
    wr[ks][1] = *(const f32x4*)(rowp + (((g0 + 1) ^ sk) << 2));
  }
}
__device__ __forceinline__ void loadX16(const short* xq, int k0, int r, int q4,
                                        bf16x8 (&xb)[2][8]) {
#pragma unroll
  for (int mf = 0; mf < 2; ++mf)
#pragma unroll
    for (int ks = 0; ks < 8; ++ks)
      xb[mf][ks] = *(const bf16x8*)(xq + (size_t)(mf * 16 + r) * KUG +
                                    k0 + ks * 32 + q4 * 8);
}
__device__ __forceinline__ void mfma8(const f32x4 (&wr)[8][2], const bf16x8 (&xb)[2][8],
                                      f32x4& aA, f32x4& aB) {
#pragma unroll
  for (int ks = 0; ks < 8; ++ks) {
    bf16x8 bb = cvt8(wr[ks][0], wr[ks][1]);
    aA = __builtin_amdgcn_mfma_f32_16x16x32_bf16(xb[0][ks], bb, aA, 0, 0, 0);
    aB = __builtin_amdgcn_mfma_f32_16x16x32_bf16(xb[1][ks], bb, aB, 0, 0, 0);
  }
}

// One 256-k tile j. On entry: evenW(j) rows 0-15 + XC loaded (vmcnt==that).
// XN receives X(j+1). LAST: j is the final tile.
template<bool LAST>
__device__ __forceinline__ void up_tile(const float* wg, const short* xq, float* wbuf,
                                        int j, int t, int r, int q4, int sk,
                                        bf16x8 (&XC)[2][8], bf16x8 (&XN)[2][8],
                                        f32x4 (&acc)[2][2]) {
  int k0 = j * 256;
  VMC0(); SCHED0();                       // evenW(j)+X(j) landed
  f32x4 wr0[8][2];
  readW8(wbuf, r, q4, sk, wr0); SCHED0(); // ds_reads issued before overwrite DMAs
  stage16_1k(wg + (size_t)16 * KUG, wbuf, k0, t);   // oddW(j): rows 16-31
  SCHED0();
  if (!LAST) { loadX16(xq, k0 + 256, r, q4, XN); SCHED0(); }  // X(j+1) rides
  mfma8(wr0, XC, acc[0][0], acc[1][0]);   // n-frag 0 (W rows 0-15)
  if (!LAST) { VMC16(); } else { VMC0(); }           // oddW landed; X(j+1) rides
  SCHED0();
  f32x4 wr1[8][2];
  readW8(wbuf, r, q4, sk, wr1); SCHED0();
  if (!LAST) { stage16_1k(wg, wbuf, k0 + 256, t); SCHED0(); } // evenW(j+1)
  mfma8(wr1, XC, acc[0][1], acc[1][1]);   // n-frag 1 (W rows 16-31)
}

// ---- DOWN path: R4's exact structure (BK=128, 512B visits), bf16 X ----
__device__ __forceinline__ void stageW32(const float* wg, float* wbuf, int k0, int t) {
#pragma unroll
  for (int i = 0; i < 16; ++i) {
    int gid = i * 64 + t;
    int row = gid >> 5;                 // 32 granules (16B) per row
    int q   = gid & 31;
    int qs  = q ^ (row & 7);
    __builtin_amdgcn_global_load_lds(
        (gbl_f32*)(wg + (size_t)row * KDN + k0 + qs * 4),
        (lds_f32*)(wbuf + gid * 4), 16, 0, 0);
  }
}

__global__ __launch_bounds__(64, 2) void moe_masked_gemm(
    const float* __restrict__ w_ug, const float* __restrict__ w_dn,
    const short* __restrict__ xbf_ug, const short* __restrict__ xbf_dn,
    const int* __restrict__ masked_m, float* __restrict__ out) {
  __shared__ float wbuf[4096];          // 16 KB (up: [16][256], down: [32][128])

  int b = blockIdx.x;
  int g = b & 7;                        // group -> XCD affinity
  int v = b >> 3;                       // unit slot 0..215
  // Bresenham 11:16 interleave (88:128 per group): balances per-CU mix of
  // long up-units vs short down-units (all-resident -> no refill -> mix matters).
  int p = v / 27, s = v - p * 27;
  int ub = (s * 11 + 16) / 27;
  bool is_up = ((s * 11) % 27) < 11;

  int mm = masked_m[g];
  int t  = threadIdx.x;
  int r  = t & 15, q4 = t >> 4, sk = r & 7;

  f32x4 acc[2][2];
#pragma unroll
  for (int mf = 0; mf < 2; ++mf)
#pragma unroll
    for (int nf = 0; nf < 2; ++nf) acc[mf][nf] = (f32x4){0.f, 0.f, 0.f, 0.f};

  int n0, colOff;
  if (is_up) {
    int u = p * 11 + ub;
    n0 = u * BN; colOff = 0;
    const float* wg = w_ug + ((size_t)g * NUG + n0) * KUG;
    const short* xq = xbf_ug + (size_t)g * M_ * KUG;
    if (mm != 0) {
      constexpr int NT = KUG / 256;     // 16 tiles
      bf16x8 xA[2][8], xB[2][8];
      stage16_1k(wg, wbuf, 0, t); SCHED0();
      loadX16(xq, 0, r, q4, xA);  SCHED0();
      for (int pp = 0; pp < NT / 2 - 1; ++pp) {
        up_tile<false>(wg, xq, wbuf, 2 * pp,     t, r, q4, sk, xA, xB, acc);
        up_tile<false>(wg, xq, wbuf, 2 * pp + 1, t, r, q4, sk, xB, xA, acc);
      }
      up_tile<false>(wg, xq, wbuf, NT - 2, t, r, q4, sk, xA, xB, acc);
      up_tile<true >(wg, xq, wbuf, NT - 1, t, r, q4, sk, xB, xA, acc);
    }
  } else {
    int d = p * 16 + (s - ub);
    n0 = d * BN; colOff = NUG;
    const float* wg = w_dn + ((size_t)g * NDN + n0) * KDN;
    const short* xq = xbf_dn + (size_t)g * M_ * KDN;
    if (mm != 0) {
      for (int it = 0; it < KDN / 128; ++it) {     // 11 iters
        int k0 = it * 128;
        stageW32(wg, wbuf, k0, t);
        bf16x8 xb[2][4];
#pragma unroll
        for (int mf = 0; mf < 2; ++mf)
#pragma unroll
          for (int ks = 0; ks < 4; ++ks)
            xb[mf][ks] = *(const bf16x8*)(xq + (size_t)(mf * 16 + r) * KDN +
                                          k0 + ks * 32 + q4 * 8);
        VMC0(); SCHED0();
#pragma unroll
        for (int ks = 0; ks < 4; ++ks) {
          int g0 = (ks * 4 + q4) * 2;
          int o0 = ((g0 ^ sk) << 2), o1 = (((g0 + 1) ^ sk) << 2);
#pragma unroll
          for (int nf = 0; nf < 2; ++nf) {
            const float* rowp = wbuf + (size_t)(nf * 16 + r) * 128;
            bf16x8 bb = cvt8(*(const f32x4*)(rowp + o0), *(const f32x4*)(rowp + o1));
            acc[0][nf] = __builtin_amdgcn_mfma_f32_16x16x32_bf16(xb[0][ks], bb, acc[0][nf], 0, 0, 0);
            acc[1][nf] = __builtin_amdgcn_mfma_f32_16x16x32_bf16(xb[1][ks], bb, acc[1][nf], 0, 0, 0);
          }
        }
      }
    }
  }

  // Epilogue. C/D layout: col = lane&15, row = (lane>>4)*4 + i (m89-verified).
  float* outg = out + (size_t)g * M_ * NOUT + colOff + n0;
#pragma unroll
  for (int i = 0; i < 4; ++i) {
    int m0 = q4 * 4 + i, m1 = 16 + m0;
    bool v0 = m0 < mm, v1 = m1 < mm;
#pragma unroll
    for (int nf = 0; nf < 2; ++nf) {
      outg[(size_t)m0 * NOUT + nf * 16 + r] = v0 ? acc[0][nf][i] : 0.f;
      outg[(size_t)m1 * NOUT + nf * 16 + r] = v1 ? acc[1][nf][i] : 0.f;
    }
  }
}

// Fallback (tiny ws): R4's exact kernel, f32 X from HBM.
__global__ __launch_bounds__(64, 2) void moe_masked_gemm_f32(
    const float* __restrict__ x_ug, const float* __restrict__ w_ug,
    const float* __restrict__ x_dn, const float* __restrict__ w_dn,
    const int* __restrict__ masked_m, float* __restrict__ out) {
  __shared__ float wbuf[4096];
  int b = blockIdx.x, g = b & 7, u = b >> 3;
  const float* wg; const float* xf;
  int K, n0, colOff, NIT;
  bool is_up = (u < UPT);
  if (is_up) { K = KUG; NIT = 32; n0 = u * BN; colOff = 0;
    wg = w_ug + ((size_t)g * NUG + n0) * KUG; xf = x_ug + (size_t)g * M_ * KUG;
  } else { int d = u - UPT; K = KDN; NIT = 11; n0 = d * BN; colOff = NUG;
    wg = w_dn + ((size_t)g * NDN + n0) * KDN; xf = x_dn + (size_t)g * M_ * KDN; }
  int mm = masked_m[g], t = threadIdx.x, r = t & 15, q4 = t >> 4, sk = r & 7;
  f32x4 acc[2][2];
#pragma unroll
  for (int mf = 0; mf < 2; ++mf)
#pragma unroll
    for (int nf = 0; nf < 2; ++nf) acc[mf][nf] = (f32x4){0.f, 0.f, 0.f, 0.f};
  if (mm != 0) {
    for (int it = 0; it < NIT; ++it) {
      int k0 = it * 128;
#pragma unroll
      for (int i = 0; i < 16; ++i) {
        int gid = i * 64 + t, row = gid >> 5, q = gid & 31, qs = q ^ (row & 7);
        __builtin_amdgcn_global_load_lds((gbl_f32*)(wg + (size_t)row * K + k0 + qs * 4),
                                         (lds_f32*)(wbuf + gid * 4), 16, 0, 0);
      }
      bf16x8 xb[2][4];
#pragma unroll
      for (int mf = 0; mf < 2; ++mf)
#pragma unroll
        for (int ks = 0; ks < 4; ++ks) {
          const float* xp = xf + (size_t)(mf * 16 + r) * K + k0 + ks * 32 + q4 * 8;
          xb[mf][ks] = cvt8(*(const f32x4*)xp, *(const f32x4*)(xp + 4));
        }
      VMC0(); SCHED0();
#pragma unroll
      for (int ks = 0; ks < 4; ++ks) {
        int g0 = (ks * 4 + q4) * 2;
        int o0 = ((g0 ^ sk) << 2), o1 = (((g0 + 1) ^ sk) << 2);
#pragma unroll
        for (int nf = 0; nf < 2; ++nf) {
          const float* rowp = wbuf + (size_t)(nf * 16 + r) * 128;
          bf16x8 bb = cvt8(*(const f32x4*)(rowp + o0), *(const f32x4*)(rowp + o1));
          acc[0][nf] = __builtin_amdgcn_mfma_f32_16x16x32_bf16(xb[0][ks], bb, acc[0][nf], 0, 0, 0);
          acc[1][nf] = __builtin_amdgcn_mfma_f32_16x16x32_bf16(xb[1][ks], bb, acc[1][nf], 0, 0, 0);
        }
      }
    }
  }
  float* outg = out + (size_t)g * M_ * NOUT + colOff + n0;
#pragma unroll
  for (int i = 0; i < 4; ++i) {
    int m0 = q4 * 4 + i, m1 = 16 + m0;
    bool v0 = m0 < mm, v1 = m1 < mm;
#pragma unroll
    for (int nf = 0; nf < 2; ++nf) {
      outg[(size_t)m0 * NOUT + nf * 16 + r] = v0 ? acc[0][nf][i] : 0.f;
      outg[(size_t)m1 * NOUT + nf * 16 + r] = v1 ? acc[1][nf][i] : 0.f;
    }
  }
}

extern "C" void kernel_launch(void* const* d_in, const int* in_sizes, int n_in,
                              void* d_out, int out_size, void* d_ws, size_t ws_size,
                              hipStream_t stream) {
  const float* x_ug     = (const float*)d_in[0];
  const float* w_ug     = (const float*)d_in[1];
  const float* x_dn     = (const float*)d_in[2];
  const float* w_dn     = (const float*)d_in[3];
  const int*   masked_m = (const int*)d_in[4];
  float*       out      = (float*)d_out;

  short* xbf_ug = (short*)d_ws;
  short* xbf_dn = xbf_ug + XUG_E;

  if (ws_size >= XBF_BYTES) {
    int n8 = (XUG_E + XDN_E) / 8;
    cvt_x_kernel<<<dim3((n8 + 255) / 256), dim3(256), 0, stream>>>(
        x_ug, x_dn, xbf_ug, xbf_dn);
    moe_masked_gemm<<<dim3(G_ * UPG), dim3(64), 0, stream>>>(
        w_ug, w_dn, xbf_ug, xbf_dn, masked_m, out);
  } else {
    moe_masked_gemm_f32<<<dim3(G_ * UPG), dim3(64), 0, stream>>>(
        x_ug, w_ug, x_dn, w_dn, masked_m, out);
  }
}

// Round 11
// 111.070 us; speedup vs baseline: 1.4772x; 1.3702x over previous
//
#include <hip/hip_runtime.h>
#include <hip/hip_bf16.h>

// Grouped masked GEMM (DeepSeekMOE up/gate + down), fp32 in/out, bf16 MFMA.
// G=8, M=32. up/gate: K=4096,N=2816. down: K=1408,N=4096. out: [G,32,5632] f32.
//
// R10 = R4 byte-exact (best, 122.9us: n=32 one-wave units, 1728 all-resident
// blocks, W via global_load_lds BK=128 = 512B row-visits, source-granule XOR
// swizzle, per-iter vmcnt(0), XCD-affine g=b&7) + ONE change: X pre-converted
// to bf16 in d_ws (halves X-side L2/L3 fabric bytes, deletes X cvt from the
// hot loop). Clean single-axis test of the fabric-bandwidth model; also
// de-confounds R7 (which bundled this with a pinned pipeline and lost).

#define G_    8
#define M_    32
#define KUG   4096
#define NUG   2816
#define KDN   1408
#define NDN   4096
#define NOUT  (NUG + NDN)      // 5632
#define BN    32
#define BK    128
#define UPT   (NUG / BN)       // 88 up units per group
#define DNT   (NDN / BN)       // 128 down units per group
#define UPG   (UPT + DNT)      // 216 units per group; grid = 1728
#define XUG_E (G_ * M_ * KUG)  // 1048576
#define XDN_E (G_ * M_ * KDN)  // 360448
#define XBF_BYTES ((size_t)(XUG_E + XDN_E) * 2)

typedef __attribute__((ext_vector_type(8))) short bf16x8;
typedef __attribute__((ext_vector_type(4))) float f32x4;

typedef __attribute__((address_space(3))) float        lds_f32;
typedef const __attribute__((address_space(1))) float  gbl_f32;

// fp32 -> bf16 RNE via compiler (m240: don't hand-write cvt_pk asm).
__device__ __forceinline__ short f2bf(float x) {
  union { __hip_bfloat16 h; short s; } u;
  u.h = __hip_bfloat16(x);
  return u.s;
}
__device__ __forceinline__ bf16x8 cvt8(f32x4 lo, f32x4 hi) {
  bf16x8 o;
#pragma unroll
  for (int j = 0; j < 4; ++j) { o[j] = f2bf(lo[j]); o[4 + j] = f2bf(hi[j]); }
  return o;
}

// Prologue: f32 -> bf16 for both X arrays, one launch (688 blocks).
__global__ void cvt_x_kernel(const float* __restrict__ xu, const float* __restrict__ xd,
                             short* __restrict__ du, short* __restrict__ dd) {
  int i = blockIdx.x * 256 + threadIdx.x;
  const float* s; short* d;
  int j = i;
  if (i < XUG_E / 8) { s = xu; d = du; }
  else { s = xd; d = dd; j = i - XUG_E / 8; if (j >= XDN_E / 8) return; }
  f32x4 lo = *(const f32x4*)(s + (size_t)j * 8);
  f32x4 hi = *(const f32x4*)(s + (size_t)j * 8 + 4);
  *(bf16x8*)(d + (size_t)j * 8) = cvt8(lo, hi);
}

// Stage W tile [32 rows][BK=128 f32] via 16 gload_lds; instr i covers rows
// {2i,2i+1}, 512B contiguous per row (R4-proven sweet spot). LDS dest linear
// (gload_lds rule); bank-swizzle by source-granule XOR:
// LDS[row][q] = glob[row][q ^ (row&7)] (involution, re-applied on read).
__device__ __forceinline__ void stageW(const float* wg, float* wbuf, int K,
                                       int k0, int t) {
#pragma unroll
  for (int i = 0; i < 16; ++i) {
    int gid = i * 64 + t;
    int row = gid >> 5;           // 32 granules (16B) per row
    int q   = gid & 31;
    int qs  = q ^ (row & 7);
    __builtin_amdgcn_global_load_lds(
        (gbl_f32*)(wg + (size_t)row * K + k0 + qs * 4),
        (lds_f32*)(wbuf + gid * 4), 16, 0, 0);
  }
}

template<bool XBF>
__global__ __launch_bounds__(64, 2) void moe_masked_gemm(
    const float* __restrict__ x_ug, const float* __restrict__ w_ug,
    const float* __restrict__ x_dn, const float* __restrict__ w_dn,
    const short* __restrict__ xbf_ug, const short* __restrict__ xbf_dn,
    const int* __restrict__ masked_m, float* __restrict__ out) {
  __shared__ float wbuf[BN * BK];   // 16 KB -> all 1728 blocks co-resident

  int b = blockIdx.x;
  int g = b & 7;                    // group -> XCD affinity (R4 mapping)
  int u = b >> 3;                   // unit 0..215: [0,88) up, [88,216) down

  const float* wg;
  const float* xf;
  const short* xq;
  int K, NIT, n0, colOff;
  bool is_up = (u < UPT);
  if (is_up) {
    K = KUG; NIT = KUG / BK; n0 = u * BN; colOff = 0;          // 32 iters
    wg = w_ug + ((size_t)g * NUG + n0) * KUG;
    xf = x_ug + (size_t)g * M_ * KUG;
    xq = xbf_ug + (size_t)g * M_ * KUG;
  } else {
    int d = u - UPT;
    K = KDN; NIT = KDN / BK; n0 = d * BN; colOff = NUG;        // 11 iters
    wg = w_dn + ((size_t)g * NDN + n0) * KDN;
    xf = x_dn + (size_t)g * M_ * KDN;
    xq = xbf_dn + (size_t)g * M_ * KDN;
  }

  int mm = masked_m[g];
  int t  = threadIdx.x;
  int r  = t & 15, q4 = t >> 4;     // frag coords
  int sk = r & 7;                   // read-side swizzle key (== row&7 for lane's rows)

  f32x4 acc[2][2];                  // [m-frag][n-frag]
#pragma unroll
  for (int mf = 0; mf < 2; ++mf)
#pragma unroll
    for (int nf = 0; nf < 2; ++nf) acc[mf][nf] = (f32x4){0.f, 0.f, 0.f, 0.f};

  if (mm != 0) {                    // mm==0: skip ALL reads, epilogue writes zeros
    for (int it = 0; it < NIT; ++it) {
      int k0 = it * BK;

      // Issue the W DMAs first, then X loads ride behind them.
      stageW(wg, wbuf, K, k0, t);

      // X fragments (L2/L3-served). bf16 path: one 16B load, MFMA layout.
      bf16x8 xb[2][4];              // [m-frag][k-step]
      if constexpr (XBF) {
#pragma unroll
        for (int mf = 0; mf < 2; ++mf)
#pragma unroll
          for (int ks = 0; ks < 4; ++ks)
            xb[mf][ks] = *(const bf16x8*)(xq + (size_t)(mf * 16 + r) * K +
                                          k0 + ks * 32 + q4 * 8);
      } else {
#pragma unroll
        for (int mf = 0; mf < 2; ++mf)
#pragma unroll
          for (int ks = 0; ks < 4; ++ks) {
            const float* xp = xf + (size_t)(mf * 16 + r) * K + k0 + ks * 32 + q4 * 8;
            xb[mf][ks] = cvt8(*(const f32x4*)xp, *(const f32x4*)(xp + 4));
          }
      }

      // gload_lds -> ds_read dep is invisible to the compiler (rule #18).
      asm volatile("s_waitcnt vmcnt(0)" ::: "memory");
      __builtin_amdgcn_sched_barrier(0);

      // 4 k-steps x (2 m-frags x 2 n-frags) = 16 MFMA, swizzle-corrected reads.
#pragma unroll
      for (int ks = 0; ks < 4; ++ks) {
        int g0 = (ks * 4 + q4) * 2;
        int o0 = ((g0 ^ sk) << 2), o1 = (((g0 + 1) ^ sk) << 2);
#pragma unroll
        for (int nf = 0; nf < 2; ++nf) {
          const float* rowp = wbuf + (size_t)(nf * 16 + r) * BK;
          bf16x8 bb = cvt8(*(const f32x4*)(rowp + o0), *(const f32x4*)(rowp + o1));
          acc[0][nf] = __builtin_amdgcn_mfma_f32_16x16x32_bf16(xb[0][ks], bb, acc[0][nf], 0, 0, 0);
          acc[1][nf] = __builtin_amdgcn_mfma_f32_16x16x32_bf16(xb[1][ks], bb, acc[1][nf], 0, 0, 0);
        }
      }
      // Next iter's gload_lds can't pass this iter's ds_reads (same LDS buffer,
      // in-order wave) — R4-validated single-buffer reuse.
    }
  }

  // Epilogue. C/D layout: col = lane&15, row = (lane>>4)*4 + i (m89-verified).
  // Lane stores cols n0 + nf*16 + r for rows m = mf*16 + q4*4 + i; mask m >= mm.
  float* outg = out + (size_t)g * M_ * NOUT + colOff + n0;
#pragma unroll
  for (int i = 0; i < 4; ++i) {
    int m0 = q4 * 4 + i, m1 = 16 + m0;
    bool v0 = m0 < mm, v1 = m1 < mm;
#pragma unroll
    for (int nf = 0; nf < 2; ++nf) {
      outg[(size_t)m0 * NOUT + nf * 16 + r] = v0 ? acc[0][nf][i] : 0.f;
      outg[(size_t)m1 * NOUT + nf * 16 + r] = v1 ? acc[1][nf][i] : 0.f;
    }
  }
}

extern "C" void kernel_launch(void* const* d_in, const int* in_sizes, int n_in,
                              void* d_out, int out_size, void* d_ws, size_t ws_size,
                              hipStream_t stream) {
  const float* x_ug     = (const float*)d_in[0];
  const float* w_ug     = (const float*)d_in[1];
  const float* x_dn     = (const float*)d_in[2];
  const float* w_dn     = (const float*)d_in[3];
  const int*   masked_m = (const int*)d_in[4];
  float*       out      = (float*)d_out;

  short* xbf_ug = (short*)d_ws;
  short* xbf_dn = xbf_ug + XUG_E;

  if (ws_size >= XBF_BYTES) {
    int n8 = (XUG_E + XDN_E) / 8;
    cvt_x_kernel<<<dim3((n8 + 255) / 256), dim3(256), 0, stream>>>(
        x_ug, x_dn, xbf_ug, xbf_dn);
    moe_masked_gemm<true><<<dim3(G_ * UPG), dim3(64), 0, stream>>>(
        x_ug, w_ug, x_dn, w_dn, xbf_ug, xbf_dn, masked_m, out);
  } else {
    moe_masked_gemm<false><<<dim3(G_ * UPG), dim3(64), 0, stream>>>(
        x_ug, w_ug, x_dn, w_dn, xbf_ug, xbf_dn, masked_m, out);
  }
}